// Round 1
// baseline (5406.951 us; speedup 1.0000x reference)
//
#include <hip/hip_runtime.h>
#include <math.h>

#define N_PIX 65536
#define S_SP  1024
#define C_IN  128
#define HIDE  128
#define OUTW  64
#define NCLS  16
#define E_A   16384
#define E_IMP 6144
#define E_PX  1048576
#define EPSV  1e-5f

// ---------------------------------------------------------------------------
// x0 = BN0(x @ prelin_w + prelin_b)       [N,128] @ [128,128]
// tile: 32 rows x 128 cols per block, 256 thr, thread = 4r x 4c, W fully in LDS
// ---------------------------------------------------------------------------
__global__ __launch_bounds__(256) void k_x0(
    const float* __restrict__ x, const float* __restrict__ W,
    const float* __restrict__ bias, const float* __restrict__ g,
    const float* __restrict__ bb, const float* __restrict__ m,
    const float* __restrict__ vv, float* __restrict__ out) {
  __shared__ float Wl[128 * 128];
  __shared__ float Xl[32 * 128];
  int t = threadIdx.x;
  int n0 = blockIdx.x * 32;
  {
    const float4* Wg = (const float4*)W;
    float4* Wd = (float4*)Wl;
#pragma unroll
    for (int i = 0; i < 16; ++i) Wd[t + 256 * i] = Wg[t + 256 * i];
    const float4* Xg = (const float4*)(x + (size_t)n0 * 128);
    float4* Xd = (float4*)Xl;
#pragma unroll
    for (int i = 0; i < 4; ++i) Xd[t + 256 * i] = Xg[t + 256 * i];
  }
  __syncthreads();
  int ht = t & 31, nt = t >> 5;
  int h0 = ht * 4, r0 = nt * 4;
  float acc[4][4];
#pragma unroll
  for (int c = 0; c < 4; ++c) {
    float bv = bias[h0 + c];
#pragma unroll
    for (int r = 0; r < 4; ++r) acc[r][c] = bv;
  }
  for (int k = 0; k < 128; k += 4) {
    float4 xr[4], wk[4];
#pragma unroll
    for (int r = 0; r < 4; ++r) xr[r] = *(const float4*)&Xl[(r0 + r) * 128 + k];
#pragma unroll
    for (int kk = 0; kk < 4; ++kk) wk[kk] = *(const float4*)&Wl[(k + kk) * 128 + h0];
#pragma unroll
    for (int r = 0; r < 4; ++r) {
      float xs[4] = {xr[r].x, xr[r].y, xr[r].z, xr[r].w};
#pragma unroll
      for (int kk = 0; kk < 4; ++kk) {
        acc[r][0] += xs[kk] * wk[kk].x;
        acc[r][1] += xs[kk] * wk[kk].y;
        acc[r][2] += xs[kk] * wk[kk].z;
        acc[r][3] += xs[kk] * wk[kk].w;
      }
    }
  }
#pragma unroll
  for (int c = 0; c < 4; ++c) {
    int h = h0 + c;
    float sc = g[h] * rsqrtf(vv[h] + EPSV);
    float mb = m[h], bo = bb[h];
#pragma unroll
    for (int r = 0; r < 4; ++r) acc[r][c] = sc * (acc[r][c] - mb) + bo;
  }
#pragma unroll
  for (int r = 0; r < 4; ++r) {
    *(float4*)&out[(size_t)(n0 + r0 + r) * 128 + h0] =
        make_float4(acc[r][0], acc[r][1], acc[r][2], acc[r][3]);
  }
}

// ---------------------------------------------------------------------------
// hp_unnorm[s,h] = sum_n Q[n,s]*x0[n,h]  (atomic k-split), also colsum[s]
// grid 256: 8 s-tiles(128) x 32 k-chunks(2048 rows). thread = 8s x 8h
// ---------------------------------------------------------------------------
__global__ __launch_bounds__(256) void k_hpu(
    const float* __restrict__ Q, const float* __restrict__ x0,
    float* __restrict__ hp, float* __restrict__ csum) {
  __shared__ float Ql[32 * 128];
  __shared__ float Xl[32 * 128];
  int t = threadIdx.x;
  int bs = blockIdx.x & 7;
  int bk = blockIdx.x >> 3;
  int s_base = bs * 128;
  int ht = t & 15, st = t >> 4;
  int h0 = ht * 8, s0 = st * 8;
  float acc[8][8];
#pragma unroll
  for (int a = 0; a < 8; ++a)
#pragma unroll
    for (int b = 0; b < 8; ++b) acc[a][b] = 0.f;
  float cs = 0.f;
  int rlo = (t < 128) ? 0 : 16;
  int scol = t & 127;
  for (int c = 0; c < 64; ++c) {
    int n0 = bk * 2048 + c * 32;
    {
      float4* Qd = (float4*)Ql;
      float4* Xd = (float4*)Xl;
      const float4* Xg = (const float4*)(x0 + (size_t)n0 * 128);
#pragma unroll
      for (int it = 0; it < 4; ++it) {
        int v = t + 256 * it;
        int i = v >> 5, sq = v & 31;
        Qd[v] = *(const float4*)&Q[(size_t)(n0 + i) * 1024 + s_base + sq * 4];
        Xd[v] = Xg[v];
      }
    }
    __syncthreads();
    for (int i = 0; i < 32; ++i) {
      float4 qa = *(const float4*)&Ql[i * 128 + s0];
      float4 qb = *(const float4*)&Ql[i * 128 + s0 + 4];
      float4 xa = *(const float4*)&Xl[i * 128 + h0];
      float4 xb = *(const float4*)&Xl[i * 128 + h0 + 4];
      float qs[8] = {qa.x, qa.y, qa.z, qa.w, qb.x, qb.y, qb.z, qb.w};
      float xv[8] = {xa.x, xa.y, xa.z, xa.w, xb.x, xb.y, xb.z, xb.w};
#pragma unroll
      for (int a = 0; a < 8; ++a)
#pragma unroll
        for (int b = 0; b < 8; ++b) acc[a][b] += qs[a] * xv[b];
    }
#pragma unroll
    for (int i = 0; i < 16; ++i) cs += Ql[(rlo + i) * 128 + scol];
    __syncthreads();
  }
  atomicAdd(&csum[s_base + scol], cs);
#pragma unroll
  for (int a = 0; a < 8; ++a)
#pragma unroll
    for (int b = 0; b < 8; ++b)
      atomicAdd(&hp[(size_t)(s_base + s0 + a) * 128 + h0 + b], acc[a][b]);
}

__global__ void k_hpnorm(float* __restrict__ hp, const float* __restrict__ csum) {
  int tid = blockIdx.x * 256 + threadIdx.x;
  hp[tid] = hp[tid] / csum[tid >> 7];
}

// ---------------------------------------------------------------------------
// htmp = hp @ W_i + b_i     [1024,128]@[128,128], 32 blocks
// ---------------------------------------------------------------------------
__global__ __launch_bounds__(256) void k_slin(
    const float* __restrict__ A, const float* __restrict__ W,
    const float* __restrict__ bias, float* __restrict__ out) {
  __shared__ float Wl[128 * 128];
  __shared__ float Xl[32 * 128];
  int t = threadIdx.x;
  int n0 = blockIdx.x * 32;
  {
    const float4* Wg = (const float4*)W;
    float4* Wd = (float4*)Wl;
#pragma unroll
    for (int i = 0; i < 16; ++i) Wd[t + 256 * i] = Wg[t + 256 * i];
    const float4* Xg = (const float4*)(A + (size_t)n0 * 128);
    float4* Xd = (float4*)Xl;
#pragma unroll
    for (int i = 0; i < 4; ++i) Xd[t + 256 * i] = Xg[t + 256 * i];
  }
  __syncthreads();
  int ht = t & 31, nt = t >> 5;
  int h0 = ht * 4, r0 = nt * 4;
  float acc[4][4];
#pragma unroll
  for (int c = 0; c < 4; ++c) {
    float bv = bias[h0 + c];
#pragma unroll
    for (int r = 0; r < 4; ++r) acc[r][c] = bv;
  }
  for (int k = 0; k < 128; k += 4) {
    float4 xr[4], wk[4];
#pragma unroll
    for (int r = 0; r < 4; ++r) xr[r] = *(const float4*)&Xl[(r0 + r) * 128 + k];
#pragma unroll
    for (int kk = 0; kk < 4; ++kk) wk[kk] = *(const float4*)&Wl[(k + kk) * 128 + h0];
#pragma unroll
    for (int r = 0; r < 4; ++r) {
      float xs[4] = {xr[r].x, xr[r].y, xr[r].z, xr[r].w};
#pragma unroll
      for (int kk = 0; kk < 4; ++kk) {
        acc[r][0] += xs[kk] * wk[kk].x;
        acc[r][1] += xs[kk] * wk[kk].y;
        acc[r][2] += xs[kk] * wk[kk].z;
        acc[r][3] += xs[kk] * wk[kk].w;
      }
    }
  }
#pragma unroll
  for (int r = 0; r < 4; ++r) {
    *(float4*)&out[(size_t)(n0 + r0 + r) * 128 + h0] =
        make_float4(acc[r][0], acc[r][1], acc[r][2], acc[r][3]);
  }
}

// ---------------------------------------------------------------------------
// MMPN edge aggregation: agg[dst] += A_val*htmp[src]; agg[dst2] += imp_val*hp[src2]
// ---------------------------------------------------------------------------
__global__ void k_edge_mmpn(
    const float* __restrict__ htmp, const float* __restrict__ hp,
    const float* __restrict__ A_val, const int* __restrict__ A_src,
    const int* __restrict__ A_dst, const float* __restrict__ imp_val,
    const int* __restrict__ imp_src, const int* __restrict__ imp_dst,
    float* __restrict__ agg) {
  long tid = (long)blockIdx.x * 256 + threadIdx.x;
  if (tid < (long)E_A * HIDE) {
    int e = (int)(tid >> 7), h = (int)(tid & 127);
    atomicAdd(&agg[(size_t)A_dst[e] * HIDE + h],
              A_val[e] * htmp[(size_t)A_src[e] * HIDE + h]);
  } else {
    long t2 = tid - (long)E_A * HIDE;
    if (t2 < (long)E_IMP * HIDE) {
      int e = (int)(t2 >> 7), h = (int)(t2 & 127);
      atomicAdd(&agg[(size_t)imp_dst[e] * HIDE + h],
                imp_val[e] * hp[(size_t)imp_src[e] * HIDE + h]);
    }
  }
}

__global__ void k_mmpn_bn(const float* __restrict__ agg, const float* __restrict__ g,
                          const float* __restrict__ b, const float* __restrict__ m,
                          const float* __restrict__ v, float* __restrict__ hp) {
  int tid = blockIdx.x * 256 + threadIdx.x;
  int h = tid & 127;
  float sc = g[h] * rsqrtf(v[h] + EPSV);
  float y = sc * (agg[tid] - m[h]) + b[h];
  hp[tid] = y >= 0.f ? y : 0.01f * y;
}

// ---------------------------------------------------------------------------
// hyp = Q @ hp    [65536,1024]@[1024,128]. tile 64 rows, k-chunks of 64 s.
// thread = 4r x 8h. Ql padded to stride 65 to break bank conflicts.
// ---------------------------------------------------------------------------
__global__ __launch_bounds__(256) void k_hyp(
    const float* __restrict__ Q, const float* __restrict__ hp,
    float* __restrict__ out) {
  __shared__ float Hl[64 * 128];   // [s][h]
  __shared__ float Ql[64 * 65];    // [n][s] padded
  int t = threadIdx.x;
  int n0 = blockIdx.x * 64;
  int ht = t & 15, nt = t >> 4;
  int h0 = ht * 8, r0 = nt * 4;
  float acc[4][8];
#pragma unroll
  for (int r = 0; r < 4; ++r)
#pragma unroll
    for (int c = 0; c < 8; ++c) acc[r][c] = 0.f;
  for (int scc = 0; scc < 16; ++scc) {
    int s0 = scc * 64;
    {
      float4* Hd = (float4*)Hl;
      const float4* Hg = (const float4*)(hp + (size_t)s0 * 128);
#pragma unroll
      for (int it = 0; it < 8; ++it) Hd[t + 256 * it] = Hg[t + 256 * it];
#pragma unroll
      for (int it = 0; it < 4; ++it) {
        int v = t + 256 * it;
        int i = v >> 4, sq = v & 15;
        float4 f = *(const float4*)&Q[(size_t)(n0 + i) * 1024 + s0 + sq * 4];
        float tmp[4] = {f.x, f.y, f.z, f.w};
#pragma unroll
        for (int u = 0; u < 4; ++u) Ql[i * 65 + sq * 4 + u] = tmp[u];
      }
    }
    __syncthreads();
    for (int s = 0; s < 64; ++s) {
      float4 ha = *(const float4*)&Hl[s * 128 + h0];
      float4 hb = *(const float4*)&Hl[s * 128 + h0 + 4];
      float hv[8] = {ha.x, ha.y, ha.z, ha.w, hb.x, hb.y, hb.z, hb.w};
#pragma unroll
      for (int r = 0; r < 4; ++r) {
        float qv = Ql[(r0 + r) * 65 + s];
#pragma unroll
        for (int c = 0; c < 8; ++c) acc[r][c] += qv * hv[c];
      }
    }
    __syncthreads();
  }
#pragma unroll
  for (int r = 0; r < 4; ++r) {
    *(float4*)&out[(size_t)(n0 + r0 + r) * 128 + h0] =
        make_float4(acc[r][0], acc[r][1], acc[r][2], acc[r][3]);
    *(float4*)&out[(size_t)(n0 + r0 + r) * 128 + h0 + 4] =
        make_float4(acc[r][4], acc[r][5], acc[r][6], acc[r][7]);
  }
}

// ---------------------------------------------------------------------------
// px linear: [N,128] @ [128,256] (rowv|colv|rowq|colq). tile 32r x 256c.
// thread = 8r x 4c, W staged in 4 k-chunks of 32.
// ---------------------------------------------------------------------------
__global__ __launch_bounds__(256) void k_pxlin(
    const float* __restrict__ px, const float* __restrict__ Wrv,
    const float* __restrict__ Wcv, const float* __restrict__ Wrq,
    const float* __restrict__ Wcq, const float* __restrict__ brv,
    const float* __restrict__ bcv, const float* __restrict__ brq,
    const float* __restrict__ bcq, float* __restrict__ out) {
  __shared__ float Xl[32 * 128];
  __shared__ float Wl[32 * 256];
  int t = threadIdx.x;
  int n0 = blockIdx.x * 32;
  {
    float4* Xd = (float4*)Xl;
    const float4* Xg = (const float4*)(px + (size_t)n0 * 128);
#pragma unroll
    for (int it = 0; it < 4; ++it) Xd[t + 256 * it] = Xg[t + 256 * it];
  }
  int ct = t & 63, nt = t >> 6;
  int c0 = ct * 4, r0 = nt * 8;
  float acc[8][4];
  {
    int mt = c0 >> 6, cb = c0 & 63;
    const float* bs = mt == 0 ? brv : mt == 1 ? bcv : mt == 2 ? brq : bcq;
#pragma unroll
    for (int c = 0; c < 4; ++c) {
      float bv = bs[cb + c];
#pragma unroll
      for (int r = 0; r < 8; ++r) acc[r][c] = bv;
    }
  }
  for (int kc = 0; kc < 4; ++kc) {
    int k0 = kc * 32;
    __syncthreads();
    {
#pragma unroll
      for (int it = 0; it < 8; ++it) {
        int v = t + 256 * it;
        int kk = v >> 6, cq = v & 63;
        int c = cq * 4;
        int mt = c >> 6, cb = c & 63;
        const float* Ws = mt == 0 ? Wrv : mt == 1 ? Wcv : mt == 2 ? Wrq : Wcq;
        *(float4*)&Wl[kk * 256 + c] = *(const float4*)&Ws[(size_t)(k0 + kk) * 64 + cb];
      }
    }
    __syncthreads();
    for (int k = 0; k < 32; k += 4) {
      float4 wq[4];
#pragma unroll
      for (int kk = 0; kk < 4; ++kk) wq[kk] = *(const float4*)&Wl[(k + kk) * 256 + c0];
#pragma unroll
      for (int r = 0; r < 8; ++r) {
        float4 xq = *(const float4*)&Xl[(r0 + r) * 128 + k0 + k];
        float xs[4] = {xq.x, xq.y, xq.z, xq.w};
#pragma unroll
        for (int kk = 0; kk < 4; ++kk) {
          acc[r][0] += xs[kk] * wq[kk].x;
          acc[r][1] += xs[kk] * wq[kk].y;
          acc[r][2] += xs[kk] * wq[kk].z;
          acc[r][3] += xs[kk] * wq[kk].w;
        }
      }
    }
  }
#pragma unroll
  for (int r = 0; r < 8; ++r) {
    *(float4*)&out[(size_t)(n0 + r0 + r) * 256 + c0] =
        make_float4(acc[r][0], acc[r][1], acc[r][2], acc[r][3]);
  }
}

// LayerNorm in place on lin4 cols [128,192) and [192,256). wave per row.
__global__ void k_ln(float* __restrict__ lin4) {
  int row = blockIdx.x * 4 + (threadIdx.x >> 6);
  int lane = threadIdx.x & 63;
  float* p = lin4 + (size_t)row * 256;
#pragma unroll
  for (int g = 0; g < 2; ++g) {
    float v = p[128 + g * 64 + lane];
    float s = v, s2 = v * v;
#pragma unroll
    for (int o = 32; o > 0; o >>= 1) {
      s += __shfl_xor(s, o, 64);
      s2 += __shfl_xor(s2, o, 64);
    }
    float mu = s * (1.0f / 64.0f);
    float var = s2 * (1.0f / 64.0f) - mu * mu;
    p[128 + g * 64 + lane] = (v - mu) * rsqrtf(var + EPSV);
  }
}

// edge scores: w[e] = exp(dot(Qv[src],Qv[dst])/64); denom[src] += w[e]
__global__ void k_escore(const float* __restrict__ lin4, int qoff,
                         const int* __restrict__ src, const int* __restrict__ dst,
                         float* __restrict__ wexp, float* __restrict__ denom) {
  int e = blockIdx.x * 256 + threadIdx.x;
  if (e >= E_PX) return;
  const float4* a = (const float4*)(lin4 + (size_t)src[e] * 256 + qoff);
  const float4* b = (const float4*)(lin4 + (size_t)dst[e] * 256 + qoff);
  float acc = 0.f;
#pragma unroll
  for (int i = 0; i < 16; ++i) {
    float4 xx = a[i], yy = b[i];
    acc += xx.x * yy.x + xx.y * yy.y + xx.z * yy.z + xx.w * yy.w;
  }
  float w = expf(acc * (1.0f / OUTW));
  wexp[e] = w;
  atomicAdd(&denom[src[e]], w);
}

// scatter: out[src, ooff+q*4 ..] += (w[e]/denom[src]) * v[dst, voff+q*4 ..]
__global__ void k_scatter(const float* __restrict__ lin4, int voff,
                          const int* __restrict__ src, const int* __restrict__ dst,
                          const float* __restrict__ wexp, const float* __restrict__ denom,
                          float* __restrict__ outp, int ooff) {
  int tid = blockIdx.x * 256 + threadIdx.x;
  int e = tid >> 4, q = tid & 15;
  if (e >= E_PX) return;
  int s = src[e];
  float coef = wexp[e] / denom[s];
  float4 v = *(const float4*)(lin4 + (size_t)dst[e] * 256 + voff + q * 4);
  float* o = outp + (size_t)s * HIDE + ooff + q * 4;
  atomicAdd(o + 0, coef * v.x);
  atomicAdd(o + 1, coef * v.y);
  atomicAdd(o + 2, coef * v.z);
  atomicAdd(o + 3, coef * v.w);
}

__global__ void k_pxbn(float* __restrict__ px, const float* __restrict__ g,
                       const float* __restrict__ b, const float* __restrict__ m,
                       const float* __restrict__ v) {
  int tid = blockIdx.x * 256 + threadIdx.x;
  int h = tid & 127;
  float x = px[tid];
  float sc = g[h] * rsqrtf(v[h] + EPSV);
  float y = sc * (x - m[h]) + b[h];
  px[tid] = y >= 0.f ? y : 0.01f * y;
}

// final: out = softmax((hyp+px) @ final_w + final_b), 16 rows/block
__global__ __launch_bounds__(256) void k_final(
    const float* __restrict__ hyp, const float* __restrict__ px,
    const float* __restrict__ W, const float* __restrict__ b,
    float* __restrict__ out) {
  __shared__ float Wl[128 * 16];
  __shared__ float rl[16 * 129];
  int t = threadIdx.x;
  int n0 = blockIdx.x * 16;
#pragma unroll
  for (int i = 0; i < 8; ++i) Wl[t + 256 * i] = W[t + 256 * i];
#pragma unroll
  for (int i = 0; i < 8; ++i) {
    int v = t + 256 * i;
    int r = v >> 7, c = v & 127;
    rl[r * 129 + c] = hyp[(size_t)(n0 + r) * 128 + c] + px[(size_t)(n0 + r) * 128 + c];
  }
  __syncthreads();
  int r = t >> 4, cls = t & 15;
  float acc = b[cls];
  for (int k = 0; k < 128; ++k) acc += rl[r * 129 + k] * Wl[k * 16 + cls];
  float mx = acc;
#pragma unroll
  for (int o = 8; o > 0; o >>= 1) mx = fmaxf(mx, __shfl_xor(mx, o, 16));
  float e = expf(acc - mx), s = e;
#pragma unroll
  for (int o = 8; o > 0; o >>= 1) s += __shfl_xor(s, o, 16);
  out[(size_t)(n0 + r) * 16 + cls] = e / s;
}

// ---------------------------------------------------------------------------
extern "C" void kernel_launch(void* const* d_in, const int* in_sizes, int n_in,
                              void* d_out, int out_size, void* d_ws, size_t ws_size,
                              hipStream_t stream) {
  const float* x        = (const float*)d_in[0];
  const float* Q        = (const float*)d_in[1];
  const float* prelin_w = (const float*)d_in[2];
  const float* prelin_b = (const float*)d_in[3];
  const float* bn0_g    = (const float*)d_in[4];
  const float* bn0_b    = (const float*)d_in[5];
  const float* bn0_m    = (const float*)d_in[6];
  const float* bn0_v    = (const float*)d_in[7];
  const float* mmpn_w   = (const float*)d_in[8];
  const float* mmpn_b   = (const float*)d_in[9];
  const float* mmpn_bn_g= (const float*)d_in[10];
  const float* mmpn_bn_b= (const float*)d_in[11];
  const float* mmpn_bn_m= (const float*)d_in[12];
  const float* mmpn_bn_v= (const float*)d_in[13];
  const float* A_val    = (const float*)d_in[14];
  const float* imp_val  = (const float*)d_in[15];
  const float* px_rowv_w= (const float*)d_in[16];
  const float* px_rowv_b= (const float*)d_in[17];
  const float* px_colv_w= (const float*)d_in[18];
  const float* px_colv_b= (const float*)d_in[19];
  const float* px_rowq_w= (const float*)d_in[20];
  const float* px_rowq_b= (const float*)d_in[21];
  const float* px_colq_w= (const float*)d_in[22];
  const float* px_colq_b= (const float*)d_in[23];
  const float* px_bn_g  = (const float*)d_in[24];
  const float* px_bn_b  = (const float*)d_in[25];
  const float* px_bn_m  = (const float*)d_in[26];
  const float* px_bn_v  = (const float*)d_in[27];
  const float* final_w  = (const float*)d_in[28];
  const float* final_b  = (const float*)d_in[29];
  const int* A_src   = (const int*)d_in[30];
  const int* A_dst   = (const int*)d_in[31];
  const int* imp_src = (const int*)d_in[32];
  const int* imp_dst = (const int*)d_in[33];
  const int* row_src = (const int*)d_in[34];
  const int* row_dst = (const int*)d_in[35];
  const int* col_src = (const int*)d_in[36];
  const int* col_dst = (const int*)d_in[37];
  float* out = (float*)d_out;

  float* ws = (float*)d_ws;
  float* x0px = ws; ws += (size_t)N_PIX * HIDE;
  float* hyp  = ws; ws += (size_t)N_PIX * HIDE;
  float* lin4 = ws; ws += (size_t)N_PIX * 256;
  float* wrow = ws; ws += E_PX;
  float* wcol = ws; ws += E_PX;
  float* drow = ws; ws += N_PIX;
  float* dcol = ws; ws += N_PIX;
  float* csum = ws; ws += S_SP;
  float* hp   = ws; ws += (size_t)S_SP * HIDE;
  float* htmp = ws; ws += (size_t)S_SP * HIDE;
  float* agg  = ws; ws += (size_t)S_SP * HIDE;

  hipMemsetAsync(csum, 0, S_SP * sizeof(float), stream);
  hipMemsetAsync(hp, 0, (size_t)S_SP * HIDE * sizeof(float), stream);

  k_x0<<<N_PIX / 32, 256, 0, stream>>>(x, prelin_w, prelin_b, bn0_g, bn0_b, bn0_m,
                                       bn0_v, x0px);
  k_hpu<<<256, 256, 0, stream>>>(Q, x0px, hp, csum);
  k_hpnorm<<<S_SP * HIDE / 256, 256, 0, stream>>>(hp, csum);

  for (int i = 0; i < 5; ++i) {
    k_slin<<<S_SP / 32, 256, 0, stream>>>(hp, mmpn_w + (size_t)i * HIDE * HIDE,
                                          mmpn_b + i * HIDE, htmp);
    hipMemsetAsync(agg, 0, (size_t)S_SP * HIDE * sizeof(float), stream);
    k_edge_mmpn<<<(E_A + E_IMP) * HIDE / 256, 256, 0, stream>>>(
        htmp, hp, A_val, A_src, A_dst, imp_val, imp_src, imp_dst, agg);
    k_mmpn_bn<<<S_SP * HIDE / 256, 256, 0, stream>>>(
        agg, mmpn_bn_g + i * HIDE, mmpn_bn_b + i * HIDE, mmpn_bn_m + i * HIDE,
        mmpn_bn_v + i * HIDE, hp);
  }

  k_hyp<<<N_PIX / 64, 256, 0, stream>>>(Q, hp, hyp);

  for (int j = 0; j < 2; ++j) {
    k_pxlin<<<N_PIX / 32, 256, 0, stream>>>(
        x0px, px_rowv_w + j * 8192, px_colv_w + j * 8192, px_rowq_w + j * 8192,
        px_colq_w + j * 8192, px_rowv_b + j * 64, px_colv_b + j * 64,
        px_rowq_b + j * 64, px_colq_b + j * 64, lin4);
    k_ln<<<N_PIX / 4, 256, 0, stream>>>(lin4);
    hipMemsetAsync(drow, 0, N_PIX * sizeof(float), stream);
    hipMemsetAsync(dcol, 0, N_PIX * sizeof(float), stream);
    k_escore<<<E_PX / 256, 256, 0, stream>>>(lin4, 128, row_src, row_dst, wrow, drow);
    k_escore<<<E_PX / 256, 256, 0, stream>>>(lin4, 192, col_src, col_dst, wcol, dcol);
    hipMemsetAsync(x0px, 0, (size_t)N_PIX * HIDE * sizeof(float), stream);
    k_scatter<<<E_PX * 16 / 256, 256, 0, stream>>>(lin4, 0, row_src, row_dst, wrow,
                                                   drow, x0px, 0);
    k_scatter<<<E_PX * 16 / 256, 256, 0, stream>>>(lin4, 64, col_src, col_dst, wcol,
                                                   dcol, x0px, 64);
    k_pxbn<<<N_PIX * HIDE / 256, 256, 0, stream>>>(x0px, px_bn_g + j * HIDE,
                                                   px_bn_b + j * HIDE,
                                                   px_bn_m + j * HIDE,
                                                   px_bn_v + j * HIDE);
  }

  k_final<<<N_PIX / 16, 256, 0, stream>>>(hyp, x0px, final_w, final_b, out);
}

// Round 2
// 2200.717 us; speedup vs baseline: 2.4569x; 2.4569x over previous
//
#include <hip/hip_runtime.h>
#include <math.h>

#define N_PIX 65536
#define S_SP  1024
#define C_IN  128
#define HIDE  128
#define OUTW  64
#define NCLS  16
#define E_A   16384
#define E_IMP 6144
#define E_PX  1048576
#define EPSV  1e-5f

// ---------------------------------------------------------------------------
// x0 = BN0(x @ prelin_w + prelin_b)       [N,128] @ [128,128]
// ---------------------------------------------------------------------------
__global__ __launch_bounds__(256) void k_x0(
    const float* __restrict__ x, const float* __restrict__ W,
    const float* __restrict__ bias, const float* __restrict__ g,
    const float* __restrict__ bb, const float* __restrict__ m,
    const float* __restrict__ vv, float* __restrict__ out) {
  __shared__ float Wl[128 * 128];
  __shared__ float Xl[32 * 128];
  int t = threadIdx.x;
  int n0 = blockIdx.x * 32;
  {
    const float4* Wg = (const float4*)W;
    float4* Wd = (float4*)Wl;
#pragma unroll
    for (int i = 0; i < 16; ++i) Wd[t + 256 * i] = Wg[t + 256 * i];
    const float4* Xg = (const float4*)(x + (size_t)n0 * 128);
    float4* Xd = (float4*)Xl;
#pragma unroll
    for (int i = 0; i < 4; ++i) Xd[t + 256 * i] = Xg[t + 256 * i];
  }
  __syncthreads();
  int ht = t & 31, nt = t >> 5;
  int h0 = ht * 4, r0 = nt * 4;
  float acc[4][4];
#pragma unroll
  for (int c = 0; c < 4; ++c) {
    float bv = bias[h0 + c];
#pragma unroll
    for (int r = 0; r < 4; ++r) acc[r][c] = bv;
  }
  for (int k = 0; k < 128; k += 4) {
    float4 xr[4], wk[4];
#pragma unroll
    for (int r = 0; r < 4; ++r) xr[r] = *(const float4*)&Xl[(r0 + r) * 128 + k];
#pragma unroll
    for (int kk = 0; kk < 4; ++kk) wk[kk] = *(const float4*)&Wl[(k + kk) * 128 + h0];
#pragma unroll
    for (int r = 0; r < 4; ++r) {
      float xs[4] = {xr[r].x, xr[r].y, xr[r].z, xr[r].w};
#pragma unroll
      for (int kk = 0; kk < 4; ++kk) {
        acc[r][0] += xs[kk] * wk[kk].x;
        acc[r][1] += xs[kk] * wk[kk].y;
        acc[r][2] += xs[kk] * wk[kk].z;
        acc[r][3] += xs[kk] * wk[kk].w;
      }
    }
  }
#pragma unroll
  for (int c = 0; c < 4; ++c) {
    int h = h0 + c;
    float sc = g[h] * rsqrtf(vv[h] + EPSV);
    float mb = m[h], bo = bb[h];
#pragma unroll
    for (int r = 0; r < 4; ++r) acc[r][c] = sc * (acc[r][c] - mb) + bo;
  }
#pragma unroll
  for (int r = 0; r < 4; ++r) {
    *(float4*)&out[(size_t)(n0 + r0 + r) * 128 + h0] =
        make_float4(acc[r][0], acc[r][1], acc[r][2], acc[r][3]);
  }
}

// ---------------------------------------------------------------------------
// hp_unnorm[s,h] = sum_n Q[n,s]*x0[n,h]  (atomic k-split), also colsum[s]
// ---------------------------------------------------------------------------
__global__ __launch_bounds__(256) void k_hpu(
    const float* __restrict__ Q, const float* __restrict__ x0,
    float* __restrict__ hp, float* __restrict__ csum) {
  __shared__ float Ql[32 * 128];
  __shared__ float Xl[32 * 128];
  int t = threadIdx.x;
  int bs = blockIdx.x & 7;
  int bk = blockIdx.x >> 3;
  int s_base = bs * 128;
  int ht = t & 15, st = t >> 4;
  int h0 = ht * 8, s0 = st * 8;
  float acc[8][8];
#pragma unroll
  for (int a = 0; a < 8; ++a)
#pragma unroll
    for (int b = 0; b < 8; ++b) acc[a][b] = 0.f;
  float cs = 0.f;
  int rlo = (t < 128) ? 0 : 16;
  int scol = t & 127;
  for (int c = 0; c < 64; ++c) {
    int n0 = bk * 2048 + c * 32;
    {
      float4* Qd = (float4*)Ql;
      float4* Xd = (float4*)Xl;
      const float4* Xg = (const float4*)(x0 + (size_t)n0 * 128);
#pragma unroll
      for (int it = 0; it < 4; ++it) {
        int v = t + 256 * it;
        int i = v >> 5, sq = v & 31;
        Qd[v] = *(const float4*)&Q[(size_t)(n0 + i) * 1024 + s_base + sq * 4];
        Xd[v] = Xg[v];
      }
    }
    __syncthreads();
    for (int i = 0; i < 32; ++i) {
      float4 qa = *(const float4*)&Ql[i * 128 + s0];
      float4 qb = *(const float4*)&Ql[i * 128 + s0 + 4];
      float4 xa = *(const float4*)&Xl[i * 128 + h0];
      float4 xb = *(const float4*)&Xl[i * 128 + h0 + 4];
      float qs[8] = {qa.x, qa.y, qa.z, qa.w, qb.x, qb.y, qb.z, qb.w};
      float xv[8] = {xa.x, xa.y, xa.z, xa.w, xb.x, xb.y, xb.z, xb.w};
#pragma unroll
      for (int a = 0; a < 8; ++a)
#pragma unroll
        for (int b = 0; b < 8; ++b) acc[a][b] += qs[a] * xv[b];
    }
#pragma unroll
    for (int i = 0; i < 16; ++i) cs += Ql[(rlo + i) * 128 + scol];
    __syncthreads();
  }
  atomicAdd(&csum[s_base + scol], cs);
#pragma unroll
  for (int a = 0; a < 8; ++a)
#pragma unroll
    for (int b = 0; b < 8; ++b)
      atomicAdd(&hp[(size_t)(s_base + s0 + a) * 128 + h0 + b], acc[a][b]);
}

__global__ void k_hpnorm(float* __restrict__ hp, const float* __restrict__ csum) {
  int tid = blockIdx.x * 256 + threadIdx.x;
  hp[tid] = hp[tid] / csum[tid >> 7];
}

// ---------------------------------------------------------------------------
// htmp = hp @ W_i + b_i     [1024,128]@[128,128]
// ---------------------------------------------------------------------------
__global__ __launch_bounds__(256) void k_slin(
    const float* __restrict__ A, const float* __restrict__ W,
    const float* __restrict__ bias, float* __restrict__ out) {
  __shared__ float Wl[128 * 128];
  __shared__ float Xl[32 * 128];
  int t = threadIdx.x;
  int n0 = blockIdx.x * 32;
  {
    const float4* Wg = (const float4*)W;
    float4* Wd = (float4*)Wl;
#pragma unroll
    for (int i = 0; i < 16; ++i) Wd[t + 256 * i] = Wg[t + 256 * i];
    const float4* Xg = (const float4*)(A + (size_t)n0 * 128);
    float4* Xd = (float4*)Xl;
#pragma unroll
    for (int i = 0; i < 4; ++i) Xd[t + 256 * i] = Xg[t + 256 * i];
  }
  __syncthreads();
  int ht = t & 31, nt = t >> 5;
  int h0 = ht * 4, r0 = nt * 4;
  float acc[4][4];
#pragma unroll
  for (int c = 0; c < 4; ++c) {
    float bv = bias[h0 + c];
#pragma unroll
    for (int r = 0; r < 4; ++r) acc[r][c] = bv;
  }
  for (int k = 0; k < 128; k += 4) {
    float4 xr[4], wk[4];
#pragma unroll
    for (int r = 0; r < 4; ++r) xr[r] = *(const float4*)&Xl[(r0 + r) * 128 + k];
#pragma unroll
    for (int kk = 0; kk < 4; ++kk) wk[kk] = *(const float4*)&Wl[(k + kk) * 128 + h0];
#pragma unroll
    for (int r = 0; r < 4; ++r) {
      float xs[4] = {xr[r].x, xr[r].y, xr[r].z, xr[r].w};
#pragma unroll
      for (int kk = 0; kk < 4; ++kk) {
        acc[r][0] += xs[kk] * wk[kk].x;
        acc[r][1] += xs[kk] * wk[kk].y;
        acc[r][2] += xs[kk] * wk[kk].z;
        acc[r][3] += xs[kk] * wk[kk].w;
      }
    }
  }
#pragma unroll
  for (int r = 0; r < 4; ++r) {
    *(float4*)&out[(size_t)(n0 + r0 + r) * 128 + h0] =
        make_float4(acc[r][0], acc[r][1], acc[r][2], acc[r][3]);
  }
}

// ---------------------------------------------------------------------------
// MMPN edge aggregation (tiny: 22K edges, atomics fine)
// ---------------------------------------------------------------------------
__global__ void k_edge_mmpn(
    const float* __restrict__ htmp, const float* __restrict__ hp,
    const float* __restrict__ A_val, const int* __restrict__ A_src,
    const int* __restrict__ A_dst, const float* __restrict__ imp_val,
    const int* __restrict__ imp_src, const int* __restrict__ imp_dst,
    float* __restrict__ agg) {
  long tid = (long)blockIdx.x * 256 + threadIdx.x;
  if (tid < (long)E_A * HIDE) {
    int e = (int)(tid >> 7), h = (int)(tid & 127);
    atomicAdd(&agg[(size_t)A_dst[e] * HIDE + h],
              A_val[e] * htmp[(size_t)A_src[e] * HIDE + h]);
  } else {
    long t2 = tid - (long)E_A * HIDE;
    if (t2 < (long)E_IMP * HIDE) {
      int e = (int)(t2 >> 7), h = (int)(t2 & 127);
      atomicAdd(&agg[(size_t)imp_dst[e] * HIDE + h],
                imp_val[e] * hp[(size_t)imp_src[e] * HIDE + h]);
    }
  }
}

__global__ void k_mmpn_bn(const float* __restrict__ agg, const float* __restrict__ g,
                          const float* __restrict__ b, const float* __restrict__ m,
                          const float* __restrict__ v, float* __restrict__ hp) {
  int tid = blockIdx.x * 256 + threadIdx.x;
  int h = tid & 127;
  float sc = g[h] * rsqrtf(v[h] + EPSV);
  float y = sc * (agg[tid] - m[h]) + b[h];
  hp[tid] = y >= 0.f ? y : 0.01f * y;
}

// ---------------------------------------------------------------------------
// hyp = Q @ hp    [65536,1024]@[1024,128]
// ---------------------------------------------------------------------------
__global__ __launch_bounds__(256) void k_hyp(
    const float* __restrict__ Q, const float* __restrict__ hp,
    float* __restrict__ out) {
  __shared__ float Hl[64 * 128];   // [s][h]
  __shared__ float Ql[64 * 65];    // [n][s] padded
  int t = threadIdx.x;
  int n0 = blockIdx.x * 64;
  int ht = t & 15, nt = t >> 4;
  int h0 = ht * 8, r0 = nt * 4;
  float acc[4][8];
#pragma unroll
  for (int r = 0; r < 4; ++r)
#pragma unroll
    for (int c = 0; c < 8; ++c) acc[r][c] = 0.f;
  for (int scc = 0; scc < 16; ++scc) {
    int s0 = scc * 64;
    {
      float4* Hd = (float4*)Hl;
      const float4* Hg = (const float4*)(hp + (size_t)s0 * 128);
#pragma unroll
      for (int it = 0; it < 8; ++it) Hd[t + 256 * it] = Hg[t + 256 * it];
#pragma unroll
      for (int it = 0; it < 4; ++it) {
        int v = t + 256 * it;
        int i = v >> 4, sq = v & 15;
        float4 f = *(const float4*)&Q[(size_t)(n0 + i) * 1024 + s0 + sq * 4];
        float tmp[4] = {f.x, f.y, f.z, f.w};
#pragma unroll
        for (int u = 0; u < 4; ++u) Ql[i * 65 + sq * 4 + u] = tmp[u];
      }
    }
    __syncthreads();
    for (int s = 0; s < 64; ++s) {
      float4 ha = *(const float4*)&Hl[s * 128 + h0];
      float4 hb = *(const float4*)&Hl[s * 128 + h0 + 4];
      float hv[8] = {ha.x, ha.y, ha.z, ha.w, hb.x, hb.y, hb.z, hb.w};
#pragma unroll
      for (int r = 0; r < 4; ++r) {
        float qv = Ql[(r0 + r) * 65 + s];
#pragma unroll
        for (int c = 0; c < 8; ++c) acc[r][c] += qv * hv[c];
      }
    }
    __syncthreads();
  }
#pragma unroll
  for (int r = 0; r < 4; ++r) {
    *(float4*)&out[(size_t)(n0 + r0 + r) * 128 + h0] =
        make_float4(acc[r][0], acc[r][1], acc[r][2], acc[r][3]);
    *(float4*)&out[(size_t)(n0 + r0 + r) * 128 + h0 + 4] =
        make_float4(acc[r][4], acc[r][5], acc[r][6], acc[r][7]);
  }
}

// ---------------------------------------------------------------------------
// px linear: [N,128] @ [128,256] (rowv|colv|rowq|colq)
// ---------------------------------------------------------------------------
__global__ __launch_bounds__(256) void k_pxlin(
    const float* __restrict__ px, const float* __restrict__ Wrv,
    const float* __restrict__ Wcv, const float* __restrict__ Wrq,
    const float* __restrict__ Wcq, const float* __restrict__ brv,
    const float* __restrict__ bcv, const float* __restrict__ brq,
    const float* __restrict__ bcq, float* __restrict__ out) {
  __shared__ float Xl[32 * 128];
  __shared__ float Wl[32 * 256];
  int t = threadIdx.x;
  int n0 = blockIdx.x * 32;
  {
    float4* Xd = (float4*)Xl;
    const float4* Xg = (const float4*)(px + (size_t)n0 * 128);
#pragma unroll
    for (int it = 0; it < 4; ++it) Xd[t + 256 * it] = Xg[t + 256 * it];
  }
  int ct = t & 63, nt = t >> 6;
  int c0 = ct * 4, r0 = nt * 8;
  float acc[8][4];
  {
    int mt = c0 >> 6, cb = c0 & 63;
    const float* bs = mt == 0 ? brv : mt == 1 ? bcv : mt == 2 ? brq : bcq;
#pragma unroll
    for (int c = 0; c < 4; ++c) {
      float bv = bs[cb + c];
#pragma unroll
      for (int r = 0; r < 8; ++r) acc[r][c] = bv;
    }
  }
  for (int kc = 0; kc < 4; ++kc) {
    int k0 = kc * 32;
    __syncthreads();
    {
#pragma unroll
      for (int it = 0; it < 8; ++it) {
        int v = t + 256 * it;
        int kk = v >> 6, cq = v & 63;
        int c = cq * 4;
        int mt = c >> 6, cb = c & 63;
        const float* Ws = mt == 0 ? Wrv : mt == 1 ? Wcv : mt == 2 ? Wrq : Wcq;
        *(float4*)&Wl[kk * 256 + c] = *(const float4*)&Ws[(size_t)(k0 + kk) * 64 + cb];
      }
    }
    __syncthreads();
    for (int k = 0; k < 32; k += 4) {
      float4 wq[4];
#pragma unroll
      for (int kk = 0; kk < 4; ++kk) wq[kk] = *(const float4*)&Wl[(k + kk) * 256 + c0];
#pragma unroll
      for (int r = 0; r < 8; ++r) {
        float4 xq = *(const float4*)&Xl[(r0 + r) * 128 + k0 + k];
        float xs[4] = {xq.x, xq.y, xq.z, xq.w};
#pragma unroll
        for (int kk = 0; kk < 4; ++kk) {
          acc[r][0] += xs[kk] * wq[kk].x;
          acc[r][1] += xs[kk] * wq[kk].y;
          acc[r][2] += xs[kk] * wq[kk].z;
          acc[r][3] += xs[kk] * wq[kk].w;
        }
      }
    }
  }
#pragma unroll
  for (int r = 0; r < 8; ++r) {
    *(float4*)&out[(size_t)(n0 + r0 + r) * 256 + c0] =
        make_float4(acc[r][0], acc[r][1], acc[r][2], acc[r][3]);
  }
}

// LayerNorm in place on lin4 cols [128,192) and [192,256). wave per row.
__global__ void k_ln(float* __restrict__ lin4) {
  int row = blockIdx.x * 4 + (threadIdx.x >> 6);
  int lane = threadIdx.x & 63;
  float* p = lin4 + (size_t)row * 256;
#pragma unroll
  for (int g = 0; g < 2; ++g) {
    float v = p[128 + g * 64 + lane];
    float s = v, s2 = v * v;
#pragma unroll
    for (int o = 32; o > 0; o >>= 1) {
      s += __shfl_xor(s, o, 64);
      s2 += __shfl_xor(s2, o, 64);
    }
    float mu = s * (1.0f / 64.0f);
    float var = s2 * (1.0f / 64.0f) - mu * mu;
    p[128 + g * 64 + lane] = (v - mu) * rsqrtf(var + EPSV);
  }
}

// ---------------------------------------------------------------------------
// CSR build: histogram -> exclusive scan -> fill
// ---------------------------------------------------------------------------
__global__ void k_hist(const int* __restrict__ src, int* __restrict__ cnt) {
  int e = blockIdx.x * 256 + threadIdx.x;
  atomicAdd(&cnt[src[e]], 1);
}

// 1 block x 1024 threads; each thread scans 64 consecutive counts.
__global__ __launch_bounds__(1024) void k_scan(const int* __restrict__ cnt,
                                               int* __restrict__ off,
                                               int* __restrict__ cur) {
  __shared__ int part[1024];
  int t = threadIdx.x;
  int base = t * 64;
  int s = 0;
  for (int i = 0; i < 64; ++i) s += cnt[base + i];
  part[t] = s;
  __syncthreads();
  for (int o = 1; o < 1024; o <<= 1) {
    int v = part[t];
    int add = (t >= o) ? part[t - o] : 0;
    __syncthreads();
    part[t] = v + add;
    __syncthreads();
  }
  int run = (t > 0) ? part[t - 1] : 0;
  for (int i = 0; i < 64; ++i) {
    off[base + i] = run;
    cur[base + i] = run;
    run += cnt[base + i];
  }
  if (t == 1023) off[65536] = run;
}

__global__ void k_fill(const int* __restrict__ src, const int* __restrict__ dst,
                       int* __restrict__ cur, int* __restrict__ csr) {
  int e = blockIdx.x * 256 + threadIdx.x;
  int p = atomicAdd(&cur[src[e]], 1);
  csr[p] = dst[e];
}

// ---------------------------------------------------------------------------
// Fused segment-softmax attention gather: one wave per output node.
// out[node, ooff+l] = sum_e w_e * V[dst_e][l] / sum_e w_e,
//   w_e = exp(dot(Qn, Q[dst_e]) / 64)
// ---------------------------------------------------------------------------
__global__ __launch_bounds__(256) void k_gather(
    const float* __restrict__ lin4, int qoff, int voff,
    const int* __restrict__ off, const int* __restrict__ csr_dst,
    float* __restrict__ outp, int ooff) {
  int node = blockIdx.x * 4 + (threadIdx.x >> 6);
  int l = threadIdx.x & 63;
  float qs = lin4[(size_t)node * 256 + qoff + l];
  int i0 = off[node], i1 = off[node + 1];
  float acc = 0.f, den = 0.f;
  for (int i = i0; i < i1; ++i) {
    int d = csr_dst[i];
    const float* base = lin4 + (size_t)d * 256;
    float qd = base[qoff + l];
    float vd = base[voff + l];
    float p = qs * qd;
#pragma unroll
    for (int o = 32; o > 0; o >>= 1) p += __shfl_xor(p, o, 64);
    float w = __expf(p * (1.0f / OUTW));
    den += w;
    acc += w * vd;
  }
  float r = den > 0.f ? 1.0f / den : 0.f;
  outp[(size_t)node * HIDE + ooff + l] = acc * r;
}

__global__ void k_pxbn(float* __restrict__ px, const float* __restrict__ g,
                       const float* __restrict__ b, const float* __restrict__ m,
                       const float* __restrict__ v) {
  int tid = blockIdx.x * 256 + threadIdx.x;
  int h = tid & 127;
  float x = px[tid];
  float sc = g[h] * rsqrtf(v[h] + EPSV);
  float y = sc * (x - m[h]) + b[h];
  px[tid] = y >= 0.f ? y : 0.01f * y;
}

// final: out = softmax((hyp+px) @ final_w + final_b), 16 rows/block
__global__ __launch_bounds__(256) void k_final(
    const float* __restrict__ hyp, const float* __restrict__ px,
    const float* __restrict__ W, const float* __restrict__ b,
    float* __restrict__ out) {
  __shared__ float Wl[128 * 16];
  __shared__ float rl[16 * 129];
  int t = threadIdx.x;
  int n0 = blockIdx.x * 16;
#pragma unroll
  for (int i = 0; i < 8; ++i) Wl[t + 256 * i] = W[t + 256 * i];
#pragma unroll
  for (int i = 0; i < 8; ++i) {
    int v = t + 256 * i;
    int r = v >> 7, c = v & 127;
    rl[r * 129 + c] = hyp[(size_t)(n0 + r) * 128 + c] + px[(size_t)(n0 + r) * 128 + c];
  }
  __syncthreads();
  int r = t >> 4, cls = t & 15;
  float acc = b[cls];
  for (int k = 0; k < 128; ++k) acc += rl[r * 129 + k] * Wl[k * 16 + cls];
  float mx = acc;
#pragma unroll
  for (int o = 8; o > 0; o >>= 1) mx = fmaxf(mx, __shfl_xor(mx, o, 16));
  float e = expf(acc - mx), s = e;
#pragma unroll
  for (int o = 8; o > 0; o >>= 1) s += __shfl_xor(s, o, 16);
  out[(size_t)(n0 + r) * 16 + cls] = e / s;
}

// ---------------------------------------------------------------------------
extern "C" void kernel_launch(void* const* d_in, const int* in_sizes, int n_in,
                              void* d_out, int out_size, void* d_ws, size_t ws_size,
                              hipStream_t stream) {
  const float* x        = (const float*)d_in[0];
  const float* Q        = (const float*)d_in[1];
  const float* prelin_w = (const float*)d_in[2];
  const float* prelin_b = (const float*)d_in[3];
  const float* bn0_g    = (const float*)d_in[4];
  const float* bn0_b    = (const float*)d_in[5];
  const float* bn0_m    = (const float*)d_in[6];
  const float* bn0_v    = (const float*)d_in[7];
  const float* mmpn_w   = (const float*)d_in[8];
  const float* mmpn_b   = (const float*)d_in[9];
  const float* mmpn_bn_g= (const float*)d_in[10];
  const float* mmpn_bn_b= (const float*)d_in[11];
  const float* mmpn_bn_m= (const float*)d_in[12];
  const float* mmpn_bn_v= (const float*)d_in[13];
  const float* A_val    = (const float*)d_in[14];
  const float* imp_val  = (const float*)d_in[15];
  const float* px_rowv_w= (const float*)d_in[16];
  const float* px_rowv_b= (const float*)d_in[17];
  const float* px_colv_w= (const float*)d_in[18];
  const float* px_colv_b= (const float*)d_in[19];
  const float* px_rowq_w= (const float*)d_in[20];
  const float* px_rowq_b= (const float*)d_in[21];
  const float* px_colq_w= (const float*)d_in[22];
  const float* px_colq_b= (const float*)d_in[23];
  const float* px_bn_g  = (const float*)d_in[24];
  const float* px_bn_b  = (const float*)d_in[25];
  const float* px_bn_m  = (const float*)d_in[26];
  const float* px_bn_v  = (const float*)d_in[27];
  const float* final_w  = (const float*)d_in[28];
  const float* final_b  = (const float*)d_in[29];
  const int* A_src   = (const int*)d_in[30];
  const int* A_dst   = (const int*)d_in[31];
  const int* imp_src = (const int*)d_in[32];
  const int* imp_dst = (const int*)d_in[33];
  const int* row_src = (const int*)d_in[34];
  const int* row_dst = (const int*)d_in[35];
  const int* col_src = (const int*)d_in[36];
  const int* col_dst = (const int*)d_in[37];
  float* out = (float*)d_out;

  float* ws = (float*)d_ws;
  float* x0px = ws; ws += (size_t)N_PIX * HIDE;
  float* hyp  = ws; ws += (size_t)N_PIX * HIDE;
  float* lin4 = ws; ws += (size_t)N_PIX * 256;
  float* csum = ws; ws += S_SP;
  float* hp   = ws; ws += (size_t)S_SP * HIDE;
  float* htmp = ws; ws += (size_t)S_SP * HIDE;   // also reused as cur_row/cur_col
  float* agg  = ws; ws += (size_t)S_SP * HIDE;   // also reused as cnt_row/cnt_col
  int* off_row = (int*)ws; ws += 65537;
  int* off_col = (int*)ws; ws += 65537;
  int* csr_row = (int*)ws; ws += E_PX;
  int* csr_col = (int*)ws; ws += E_PX;

  // cnt/cur alias agg/htmp (free after the MMPN loop)
  int* cnt_row = (int*)agg;
  int* cnt_col = (int*)agg + 65536;
  int* cur_row = (int*)htmp;
  int* cur_col = (int*)htmp + 65536;

  hipMemsetAsync(csum, 0, S_SP * sizeof(float), stream);
  hipMemsetAsync(hp, 0, (size_t)S_SP * HIDE * sizeof(float), stream);

  k_x0<<<N_PIX / 32, 256, 0, stream>>>(x, prelin_w, prelin_b, bn0_g, bn0_b, bn0_m,
                                       bn0_v, x0px);
  k_hpu<<<256, 256, 0, stream>>>(Q, x0px, hp, csum);
  k_hpnorm<<<S_SP * HIDE / 256, 256, 0, stream>>>(hp, csum);

  for (int i = 0; i < 5; ++i) {
    k_slin<<<S_SP / 32, 256, 0, stream>>>(hp, mmpn_w + (size_t)i * HIDE * HIDE,
                                          mmpn_b + i * HIDE, htmp);
    hipMemsetAsync(agg, 0, (size_t)S_SP * HIDE * sizeof(float), stream);
    k_edge_mmpn<<<(E_A + E_IMP) * HIDE / 256, 256, 0, stream>>>(
        htmp, hp, A_val, A_src, A_dst, imp_val, imp_src, imp_dst, agg);
    k_mmpn_bn<<<S_SP * HIDE / 256, 256, 0, stream>>>(
        agg, mmpn_bn_g + i * HIDE, mmpn_bn_b + i * HIDE, mmpn_bn_m + i * HIDE,
        mmpn_bn_v + i * HIDE, hp);
  }

  k_hyp<<<N_PIX / 64, 256, 0, stream>>>(Q, hp, hyp);

  // ---- CSR build (after MMPN so cnt/cur can alias agg/htmp) ----
  hipMemsetAsync(cnt_row, 0, 2 * 65536 * sizeof(int), stream);
  k_hist<<<E_PX / 256, 256, 0, stream>>>(row_src, cnt_row);
  k_hist<<<E_PX / 256, 256, 0, stream>>>(col_src, cnt_col);
  k_scan<<<1, 1024, 0, stream>>>(cnt_row, off_row, cur_row);
  k_scan<<<1, 1024, 0, stream>>>(cnt_col, off_col, cur_col);
  k_fill<<<E_PX / 256, 256, 0, stream>>>(row_src, row_dst, cur_row, csr_row);
  k_fill<<<E_PX / 256, 256, 0, stream>>>(col_src, col_dst, cur_col, csr_col);

  for (int j = 0; j < 2; ++j) {
    k_pxlin<<<N_PIX / 32, 256, 0, stream>>>(
        x0px, px_rowv_w + j * 8192, px_colv_w + j * 8192, px_rowq_w + j * 8192,
        px_colq_w + j * 8192, px_rowv_b + j * 64, px_colv_b + j * 64,
        px_rowq_b + j * 64, px_colq_b + j * 64, lin4);
    k_ln<<<N_PIX / 4, 256, 0, stream>>>(lin4);
    k_gather<<<N_PIX / 4, 256, 0, stream>>>(lin4, 128, 0, off_row, csr_row, x0px, 0);
    k_gather<<<N_PIX / 4, 256, 0, stream>>>(lin4, 192, 64, off_col, csr_col, x0px, 64);
    k_pxbn<<<N_PIX * HIDE / 256, 256, 0, stream>>>(x0px, px_bn_g + j * HIDE,
                                                   px_bn_b + j * HIDE,
                                                   px_bn_m + j * HIDE,
                                                   px_bn_v + j * HIDE);
  }

  k_final<<<N_PIX / 16, 256, 0, stream>>>(hyp, x0px, final_w, final_b, out);
}

// Round 3
// 1932.673 us; speedup vs baseline: 2.7977x; 1.1387x over previous
//
#include <hip/hip_runtime.h>
#include <math.h>

#define N_PIX 65536
#define S_SP  1024
#define C_IN  128
#define HIDE  128
#define OUTW  64
#define NCLS  16
#define E_A   16384
#define E_IMP 6144
#define E_PX  1048576
#define EPSV  1e-5f

typedef __attribute__((ext_vector_type(4))) float f32x4;
typedef __attribute__((ext_vector_type(8))) short bf16x8;

__device__ inline ushort f2bf(float f) {
  uint u = __builtin_bit_cast(uint, f);
  uint r = (u + 0x7FFFu + ((u >> 16) & 1u)) >> 16;
  return (ushort)r;
}

// ---------------------------------------------------------------------------
// x0 = BN0(x @ prelin_w + prelin_b)       [N,128] @ [128,128]  (fp32)
// ---------------------------------------------------------------------------
__global__ __launch_bounds__(256) void k_x0(
    const float* __restrict__ x, const float* __restrict__ W,
    const float* __restrict__ bias, const float* __restrict__ g,
    const float* __restrict__ bb, const float* __restrict__ m,
    const float* __restrict__ vv, float* __restrict__ out) {
  __shared__ float Wl[128 * 128];
  __shared__ float Xl[32 * 128];
  int t = threadIdx.x;
  int n0 = blockIdx.x * 32;
  {
    const float4* Wg = (const float4*)W;
    float4* Wd = (float4*)Wl;
#pragma unroll
    for (int i = 0; i < 16; ++i) Wd[t + 256 * i] = Wg[t + 256 * i];
    const float4* Xg = (const float4*)(x + (size_t)n0 * 128);
    float4* Xd = (float4*)Xl;
#pragma unroll
    for (int i = 0; i < 4; ++i) Xd[t + 256 * i] = Xg[t + 256 * i];
  }
  __syncthreads();
  int ht = t & 31, nt = t >> 5;
  int h0 = ht * 4, r0 = nt * 4;
  float acc[4][4];
#pragma unroll
  for (int c = 0; c < 4; ++c) {
    float bv = bias[h0 + c];
#pragma unroll
    for (int r = 0; r < 4; ++r) acc[r][c] = bv;
  }
  for (int k = 0; k < 128; k += 4) {
    float4 xr[4], wk[4];
#pragma unroll
    for (int r = 0; r < 4; ++r) xr[r] = *(const float4*)&Xl[(r0 + r) * 128 + k];
#pragma unroll
    for (int kk = 0; kk < 4; ++kk) wk[kk] = *(const float4*)&Wl[(k + kk) * 128 + h0];
#pragma unroll
    for (int r = 0; r < 4; ++r) {
      float xs[4] = {xr[r].x, xr[r].y, xr[r].z, xr[r].w};
#pragma unroll
      for (int kk = 0; kk < 4; ++kk) {
        acc[r][0] += xs[kk] * wk[kk].x;
        acc[r][1] += xs[kk] * wk[kk].y;
        acc[r][2] += xs[kk] * wk[kk].z;
        acc[r][3] += xs[kk] * wk[kk].w;
      }
    }
  }
#pragma unroll
  for (int c = 0; c < 4; ++c) {
    int h = h0 + c;
    float sc = g[h] * rsqrtf(vv[h] + EPSV);
    float mb = m[h], bo = bb[h];
#pragma unroll
    for (int r = 0; r < 4; ++r) acc[r][c] = sc * (acc[r][c] - mb) + bo;
  }
#pragma unroll
  for (int r = 0; r < 4; ++r) {
    *(float4*)&out[(size_t)(n0 + r0 + r) * 128 + h0] =
        make_float4(acc[r][0], acc[r][1], acc[r][2], acc[r][3]);
  }
}

// ---------------------------------------------------------------------------
// k_cast: Q fp32 [N,1024] -> Qt bf16 [1024][N] + csum[s] (exact fp32 col sums)
// block tile: 256 n x 64 s; per-thread 4x4 register micro-transpose.
// ---------------------------------------------------------------------------
__global__ __launch_bounds__(256) void k_cast(
    const float* __restrict__ Q, ushort* __restrict__ Qt,
    float* __restrict__ csum) {
  __shared__ ushort Ot[64 * 258];  // [s][n] pad 2
  __shared__ float Cs[64];
  int t = threadIdx.x;
  int nt = blockIdx.x & 255, st = blockIdx.x >> 8;
  int n0 = nt * 256, s0 = st * 64;
  int lr = t & 15, lg = t >> 4;
  if (t < 64) Cs[t] = 0.f;
  __syncthreads();
  float sums[4] = {0.f, 0.f, 0.f, 0.f};
#pragma unroll
  for (int nb = 0; nb < 4; ++nb) {
    ushort hh[4][4];
#pragma unroll
    for (int u = 0; u < 4; ++u) {
      int n = n0 + nb * 64 + lg * 4 + u;
      float4 q = *(const float4*)&Q[(size_t)n * 1024 + s0 + lr * 4];
      sums[0] += q.x; sums[1] += q.y; sums[2] += q.z; sums[3] += q.w;
      hh[u][0] = f2bf(q.x); hh[u][1] = f2bf(q.y);
      hh[u][2] = f2bf(q.z); hh[u][3] = f2bf(q.w);
    }
#pragma unroll
    for (int v = 0; v < 4; ++v) {
      uint lo = (uint)hh[0][v] | ((uint)hh[1][v] << 16);
      uint hi = (uint)hh[2][v] | ((uint)hh[3][v] << 16);
      ushort* p = &Ot[(lr * 4 + v) * 258 + nb * 64 + lg * 4];
      *(uint*)p = lo;
      *(uint*)(p + 2) = hi;
    }
  }
#pragma unroll
  for (int v = 0; v < 4; ++v) atomicAdd(&Cs[lr * 4 + v], sums[v]);
  __syncthreads();
  if (t < 64) atomicAdd(&csum[s0 + t], Cs[t]);
#pragma unroll
  for (int i = 0; i < 16; ++i) {
    int v2 = i * 256 + t;
    int s_loc = v2 >> 6, nq = v2 & 63;
    const ushort* p = &Ot[s_loc * 258 + nq * 4];
    uint2 o;
    o.x = *(const uint*)p;
    o.y = *(const uint*)(p + 2);
    *(uint2*)&Qt[(size_t)(s0 + s_loc) * 65536 + n0 + nq * 4] = o;
  }
}

// ---------------------------------------------------------------------------
// k_xT: x0 fp32 [N,128] -> x0T bf16 [128][N]
// ---------------------------------------------------------------------------
__global__ __launch_bounds__(256) void k_xT(
    const float* __restrict__ x0, ushort* __restrict__ x0T) {
  __shared__ ushort Ot[128 * 258];  // 66 KB
  int t = threadIdx.x;
  int n0 = blockIdx.x * 256;
  int lr = t & 31, lg = t >> 5;
#pragma unroll
  for (int nb = 0; nb < 8; ++nb) {
    ushort hh[4][4];
#pragma unroll
    for (int u = 0; u < 4; ++u) {
      int n = n0 + nb * 32 + lg * 4 + u;
      float4 q = *(const float4*)&x0[(size_t)n * 128 + lr * 4];
      hh[u][0] = f2bf(q.x); hh[u][1] = f2bf(q.y);
      hh[u][2] = f2bf(q.z); hh[u][3] = f2bf(q.w);
    }
#pragma unroll
    for (int v = 0; v < 4; ++v) {
      uint lo = (uint)hh[0][v] | ((uint)hh[1][v] << 16);
      uint hi = (uint)hh[2][v] | ((uint)hh[3][v] << 16);
      ushort* p = &Ot[(lr * 4 + v) * 258 + nb * 32 + lg * 4];
      *(uint*)p = lo;
      *(uint*)(p + 2) = hi;
    }
  }
  __syncthreads();
#pragma unroll
  for (int i = 0; i < 32; ++i) {
    int v2 = i * 256 + t;
    int h = v2 >> 6, nq = v2 & 63;
    const ushort* p = &Ot[h * 258 + nq * 4];
    uint2 o;
    o.x = *(const uint*)p;
    o.y = *(const uint*)(p + 2);
    *(uint2*)&x0T[(size_t)h * 65536 + n0 + nq * 4] = o;
  }
}

// ---------------------------------------------------------------------------
// k_hpT: hp fp32 [1024][128] -> hpT bf16 [128][1024]
// ---------------------------------------------------------------------------
__global__ __launch_bounds__(256) void k_hpT(
    const float* __restrict__ hp, ushort* __restrict__ hpT) {
  __shared__ ushort Ot[128 * 258];
  int t = threadIdx.x;
  int s0 = blockIdx.x * 256;
  int lr = t & 31, lg = t >> 5;
#pragma unroll
  for (int sb = 0; sb < 8; ++sb) {
    ushort hh[4][4];
#pragma unroll
    for (int u = 0; u < 4; ++u) {
      int s = s0 + sb * 32 + lg * 4 + u;
      float4 q = *(const float4*)&hp[(size_t)s * 128 + lr * 4];
      hh[u][0] = f2bf(q.x); hh[u][1] = f2bf(q.y);
      hh[u][2] = f2bf(q.z); hh[u][3] = f2bf(q.w);
    }
#pragma unroll
    for (int v = 0; v < 4; ++v) {
      uint lo = (uint)hh[0][v] | ((uint)hh[1][v] << 16);
      uint hi = (uint)hh[2][v] | ((uint)hh[3][v] << 16);
      ushort* p = &Ot[(lr * 4 + v) * 258 + sb * 32 + lg * 4];
      *(uint*)p = lo;
      *(uint*)(p + 2) = hi;
    }
  }
  __syncthreads();
#pragma unroll
  for (int i = 0; i < 32; ++i) {
    int v2 = i * 256 + t;
    int h = v2 >> 6, sq = v2 & 63;
    const ushort* p = &Ot[h * 258 + sq * 4];
    uint2 o;
    o.x = *(const uint*)p;
    o.y = *(const uint*)(p + 2);
    *(uint2*)&hpT[(size_t)h * 1024 + s0 + sq * 4] = o;
  }
}

// ---------------------------------------------------------------------------
// k_hpu: hp_part[kb][s][h] = Qt[s-range][n-range] . x0T[h][n-range]^T (MFMA)
// grid = 4 (s-tiles of 256) x 64 (k-splits of 1024 n). 4 waves x (64s x 128h).
// ---------------------------------------------------------------------------
__global__ __launch_bounds__(256) void k_hpu(
    const ushort* __restrict__ Qt, const ushort* __restrict__ x0T,
    float* __restrict__ hp_part) {
  __shared__ ushort Al[256 * 72];  // [s][k] pad to 72 shorts/row
  __shared__ ushort Bl[128 * 72];  // [h][k]
  int t = threadIdx.x;
  int mt = blockIdx.x & 3;
  int kb = blockIdx.x >> 2;
  int s_base = mt * 256;
  int n_base = kb * 1024;
  int wv = t >> 6, lane = t & 63;
  int lr = lane & 15, lq = lane >> 4;
  f32x4 acc[4][8];
#pragma unroll
  for (int i = 0; i < 4; ++i)
#pragma unroll
    for (int j = 0; j < 8; ++j) acc[i][j] = (f32x4){0.f, 0.f, 0.f, 0.f};
  for (int c = 0; c < 16; ++c) {
    int nc = n_base + c * 64;
#pragma unroll
    for (int i = 0; i < 8; ++i) {
      int v = i * 256 + t;
      int r = v >> 3, sg = v & 7;
      *(uint4*)&Al[r * 72 + sg * 8] =
          *(const uint4*)&Qt[(size_t)(s_base + r) * 65536 + nc + sg * 8];
    }
#pragma unroll
    for (int i = 0; i < 4; ++i) {
      int v = i * 256 + t;
      int r = v >> 3, sg = v & 7;
      *(uint4*)&Bl[r * 72 + sg * 8] =
          *(const uint4*)&x0T[(size_t)r * 65536 + nc + sg * 8];
    }
    __syncthreads();
#pragma unroll
    for (int kh = 0; kh < 2; ++kh) {
      bf16x8 af[4], bfr[8];
#pragma unroll
      for (int i = 0; i < 4; ++i)
        af[i] = *(const bf16x8*)&Al[(wv * 64 + i * 16 + lr) * 72 + kh * 32 + lq * 8];
#pragma unroll
      for (int j = 0; j < 8; ++j)
        bfr[j] = *(const bf16x8*)&Bl[(j * 16 + lr) * 72 + kh * 32 + lq * 8];
#pragma unroll
      for (int i = 0; i < 4; ++i)
#pragma unroll
        for (int j = 0; j < 8; ++j)
          acc[i][j] = __builtin_amdgcn_mfma_f32_16x16x32_bf16(af[i], bfr[j],
                                                              acc[i][j], 0, 0, 0);
    }
    __syncthreads();
  }
  float* outp = hp_part + (size_t)kb * 131072;
#pragma unroll
  for (int i = 0; i < 4; ++i) {
    int s_g = s_base + wv * 64 + i * 16 + lq * 4;
#pragma unroll
    for (int j = 0; j < 8; ++j) {
      int h = j * 16 + lr;
#pragma unroll
      for (int r = 0; r < 4; ++r)
        outp[(size_t)(s_g + r) * 128 + h] = acc[i][j][r];
    }
  }
}

__global__ void k_hpred(const float* __restrict__ part,
                        const float* __restrict__ csum, float* __restrict__ hp) {
  int tid = blockIdx.x * 256 + threadIdx.x;
  float s = 0.f;
  for (int kb = 0; kb < 64; ++kb) s += part[(size_t)kb * 131072 + tid];
  hp[tid] = s / csum[tid >> 7];
}

// ---------------------------------------------------------------------------
// k_hyp: hyp[n][h] = Q[n][s] . hp[s][h]  (A from fp32 Q, convert on stage)
// grid 256 (n-tiles of 256). 4 waves x (64n x 128h). K=1024, chunks of 64.
// ---------------------------------------------------------------------------
__global__ __launch_bounds__(256) void k_hyp(
    const float* __restrict__ Q, const ushort* __restrict__ hpT,
    float* __restrict__ hyp) {
  __shared__ ushort Al[256 * 72];
  __shared__ ushort Bl[128 * 72];
  int t = threadIdx.x;
  int n_base = blockIdx.x * 256;
  int wv = t >> 6, lane = t & 63;
  int lr = lane & 15, lq = lane >> 4;
  f32x4 acc[4][8];
#pragma unroll
  for (int i = 0; i < 4; ++i)
#pragma unroll
    for (int j = 0; j < 8; ++j) acc[i][j] = (f32x4){0.f, 0.f, 0.f, 0.f};
  for (int c = 0; c < 16; ++c) {
    int sc = c * 64;
#pragma unroll
    for (int i = 0; i < 16; ++i) {
      int v = i * 256 + t;
      int r = v >> 4, sq = v & 15;
      float4 f = *(const float4*)&Q[(size_t)(n_base + r) * 1024 + sc + sq * 4];
      uint2 pk;
      pk.x = (uint)f2bf(f.x) | ((uint)f2bf(f.y) << 16);
      pk.y = (uint)f2bf(f.z) | ((uint)f2bf(f.w) << 16);
      *(uint2*)&Al[r * 72 + sq * 4] = pk;
    }
#pragma unroll
    for (int i = 0; i < 4; ++i) {
      int v = i * 256 + t;
      int r = v >> 3, sg = v & 7;
      *(uint4*)&Bl[r * 72 + sg * 8] =
          *(const uint4*)&hpT[(size_t)r * 1024 + sc + sg * 8];
    }
    __syncthreads();
#pragma unroll
    for (int kh = 0; kh < 2; ++kh) {
      bf16x8 af[4], bfr[8];
#pragma unroll
      for (int i = 0; i < 4; ++i)
        af[i] = *(const bf16x8*)&Al[(wv * 64 + i * 16 + lr) * 72 + kh * 32 + lq * 8];
#pragma unroll
      for (int j = 0; j < 8; ++j)
        bfr[j] = *(const bf16x8*)&Bl[(j * 16 + lr) * 72 + kh * 32 + lq * 8];
#pragma unroll
      for (int i = 0; i < 4; ++i)
#pragma unroll
        for (int j = 0; j < 8; ++j)
          acc[i][j] = __builtin_amdgcn_mfma_f32_16x16x32_bf16(af[i], bfr[j],
                                                              acc[i][j], 0, 0, 0);
    }
    __syncthreads();
  }
#pragma unroll
  for (int i = 0; i < 4; ++i) {
    int n_g = n_base + wv * 64 + i * 16 + lq * 4;
#pragma unroll
    for (int j = 0; j < 8; ++j) {
      int h = j * 16 + lr;
#pragma unroll
      for (int r = 0; r < 4; ++r)
        hyp[(size_t)(n_g + r) * 128 + h] = acc[i][j][r];
    }
  }
}

// ---------------------------------------------------------------------------
// htmp = hp @ W_i + b_i     [1024,128]@[128,128]  (fp32, small)
// ---------------------------------------------------------------------------
__global__ __launch_bounds__(256) void k_slin(
    const float* __restrict__ A, const float* __restrict__ W,
    const float* __restrict__ bias, float* __restrict__ out) {
  __shared__ float Wl[128 * 128];
  __shared__ float Xl[32 * 128];
  int t = threadIdx.x;
  int n0 = blockIdx.x * 32;
  {
    const float4* Wg = (const float4*)W;
    float4* Wd = (float4*)Wl;
#pragma unroll
    for (int i = 0; i < 16; ++i) Wd[t + 256 * i] = Wg[t + 256 * i];
    const float4* Xg = (const float4*)(A + (size_t)n0 * 128);
    float4* Xd = (float4*)Xl;
#pragma unroll
    for (int i = 0; i < 4; ++i) Xd[t + 256 * i] = Xg[t + 256 * i];
  }
  __syncthreads();
  int ht = t & 31, nt = t >> 5;
  int h0 = ht * 4, r0 = nt * 4;
  float acc[4][4];
#pragma unroll
  for (int c = 0; c < 4; ++c) {
    float bv = bias[h0 + c];
#pragma unroll
    for (int r = 0; r < 4; ++r) acc[r][c] = bv;
  }
  for (int k = 0; k < 128; k += 4) {
    float4 xr[4], wk[4];
#pragma unroll
    for (int r = 0; r < 4; ++r) xr[r] = *(const float4*)&Xl[(r0 + r) * 128 + k];
#pragma unroll
    for (int kk = 0; kk < 4; ++kk) wk[kk] = *(const float4*)&Wl[(k + kk) * 128 + h0];
#pragma unroll
    for (int r = 0; r < 4; ++r) {
      float xs[4] = {xr[r].x, xr[r].y, xr[r].z, xr[r].w};
#pragma unroll
      for (int kk = 0; kk < 4; ++kk) {
        acc[r][0] += xs[kk] * wk[kk].x;
        acc[r][1] += xs[kk] * wk[kk].y;
        acc[r][2] += xs[kk] * wk[kk].z;
        acc[r][3] += xs[kk] * wk[kk].w;
      }
    }
  }
#pragma unroll
  for (int r = 0; r < 4; ++r) {
    *(float4*)&out[(size_t)(n0 + r0 + r) * 128 + h0] =
        make_float4(acc[r][0], acc[r][1], acc[r][2], acc[r][3]);
  }
}

// ---------------------------------------------------------------------------
// MMPN edge aggregation (tiny: 22K edges, atomics fine)
// ---------------------------------------------------------------------------
__global__ void k_edge_mmpn(
    const float* __restrict__ htmp, const float* __restrict__ hp,
    const float* __restrict__ A_val, const int* __restrict__ A_src,
    const int* __restrict__ A_dst, const float* __restrict__ imp_val,
    const int* __restrict__ imp_src, const int* __restrict__ imp_dst,
    float* __restrict__ agg) {
  long tid = (long)blockIdx.x * 256 + threadIdx.x;
  if (tid < (long)E_A * HIDE) {
    int e = (int)(tid >> 7), h = (int)(tid & 127);
    atomicAdd(&agg[(size_t)A_dst[e] * HIDE + h],
              A_val[e] * htmp[(size_t)A_src[e] * HIDE + h]);
  } else {
    long t2 = tid - (long)E_A * HIDE;
    if (t2 < (long)E_IMP * HIDE) {
      int e = (int)(t2 >> 7), h = (int)(t2 & 127);
      atomicAdd(&agg[(size_t)imp_dst[e] * HIDE + h],
                imp_val[e] * hp[(size_t)imp_src[e] * HIDE + h]);
    }
  }
}

__global__ void k_mmpn_bn(const float* __restrict__ agg, const float* __restrict__ g,
                          const float* __restrict__ b, const float* __restrict__ m,
                          const float* __restrict__ v, float* __restrict__ hp) {
  int tid = blockIdx.x * 256 + threadIdx.x;
  int h = tid & 127;
  float sc = g[h] * rsqrtf(v[h] + EPSV);
  float y = sc * (agg[tid] - m[h]) + b[h];
  hp[tid] = y >= 0.f ? y : 0.01f * y;
}

// ---------------------------------------------------------------------------
// px linear: [N,128] @ [128,256] (rowv|colv|rowq|colq)  (fp32)
// ---------------------------------------------------------------------------
__global__ __launch_bounds__(256) void k_pxlin(
    const float* __restrict__ px, const float* __restrict__ Wrv,
    const float* __restrict__ Wcv, const float* __restrict__ Wrq,
    const float* __restrict__ Wcq, const float* __restrict__ brv,
    const float* __restrict__ bcv, const float* __restrict__ brq,
    const float* __restrict__ bcq, float* __restrict__ out) {
  __shared__ float Xl[32 * 128];
  __shared__ float Wl[32 * 256];
  int t = threadIdx.x;
  int n0 = blockIdx.x * 32;
  {
    float4* Xd = (float4*)Xl;
    const float4* Xg = (const float4*)(px + (size_t)n0 * 128);
#pragma unroll
    for (int it = 0; it < 4; ++it) Xd[t + 256 * it] = Xg[t + 256 * it];
  }
  int ct = t & 63, nt = t >> 6;
  int c0 = ct * 4, r0 = nt * 8;
  float acc[8][4];
  {
    int mt = c0 >> 6, cb = c0 & 63;
    const float* bs = mt == 0 ? brv : mt == 1 ? bcv : mt == 2 ? brq : bcq;
#pragma unroll
    for (int c = 0; c < 4; ++c) {
      float bv = bs[cb + c];
#pragma unroll
      for (int r = 0; r < 8; ++r) acc[r][c] = bv;
    }
  }
  for (int kc = 0; kc < 4; ++kc) {
    int k0 = kc * 32;
    __syncthreads();
    {
#pragma unroll
      for (int it = 0; it < 8; ++it) {
        int v = t + 256 * it;
        int kk = v >> 6, cq = v & 63;
        int c = cq * 4;
        int mt = c >> 6, cb = c & 63;
        const float* Ws = mt == 0 ? Wrv : mt == 1 ? Wcv : mt == 2 ? Wrq : Wcq;
        *(float4*)&Wl[kk * 256 + c] = *(const float4*)&Ws[(size_t)(k0 + kk) * 64 + cb];
      }
    }
    __syncthreads();
    for (int k = 0; k < 32; k += 4) {
      float4 wq[4];
#pragma unroll
      for (int kk = 0; kk < 4; ++kk) wq[kk] = *(const float4*)&Wl[(k + kk) * 256 + c0];
#pragma unroll
      for (int r = 0; r < 8; ++r) {
        float4 xq = *(const float4*)&Xl[(r0 + r) * 128 + k0 + k];
        float xs[4] = {xq.x, xq.y, xq.z, xq.w};
#pragma unroll
        for (int kk = 0; kk < 4; ++kk) {
          acc[r][0] += xs[kk] * wq[kk].x;
          acc[r][1] += xs[kk] * wq[kk].y;
          acc[r][2] += xs[kk] * wq[kk].z;
          acc[r][3] += xs[kk] * wq[kk].w;
        }
      }
    }
  }
#pragma unroll
  for (int r = 0; r < 8; ++r) {
    *(float4*)&out[(size_t)(n0 + r0 + r) * 256 + c0] =
        make_float4(acc[r][0], acc[r][1], acc[r][2], acc[r][3]);
  }
}

// LayerNorm in place on lin4 cols [128,192) and [192,256). wave per row.
__global__ void k_ln(float* __restrict__ lin4) {
  int row = blockIdx.x * 4 + (threadIdx.x >> 6);
  int lane = threadIdx.x & 63;
  float* p = lin4 + (size_t)row * 256;
#pragma unroll
  for (int g = 0; g < 2; ++g) {
    float v = p[128 + g * 64 + lane];
    float s = v, s2 = v * v;
#pragma unroll
    for (int o = 32; o > 0; o >>= 1) {
      s += __shfl_xor(s, o, 64);
      s2 += __shfl_xor(s2, o, 64);
    }
    float mu = s * (1.0f / 64.0f);
    float var = s2 * (1.0f / 64.0f) - mu * mu;
    p[128 + g * 64 + lane] = (v - mu) * rsqrtf(var + EPSV);
  }
}

// ---------------------------------------------------------------------------
// CSR build: histogram -> exclusive scan -> fill
// ---------------------------------------------------------------------------
__global__ void k_hist(const int* __restrict__ src, int* __restrict__ cnt) {
  int e = blockIdx.x * 256 + threadIdx.x;
  atomicAdd(&cnt[src[e]], 1);
}

__global__ __launch_bounds__(1024) void k_scan(const int* __restrict__ cnt,
                                               int* __restrict__ off,
                                               int* __restrict__ cur) {
  __shared__ int part[1024];
  int t = threadIdx.x;
  int base = t * 64;
  int s = 0;
  for (int i = 0; i < 64; ++i) s += cnt[base + i];
  part[t] = s;
  __syncthreads();
  for (int o = 1; o < 1024; o <<= 1) {
    int v = part[t];
    int add = (t >= o) ? part[t - o] : 0;
    __syncthreads();
    part[t] = v + add;
    __syncthreads();
  }
  int run = (t > 0) ? part[t - 1] : 0;
  for (int i = 0; i < 64; ++i) {
    off[base + i] = run;
    cur[base + i] = run;
    run += cnt[base + i];
  }
  if (t == 1023) off[65536] = run;
}

__global__ void k_fill(const int* __restrict__ src, const int* __restrict__ dst,
                       int* __restrict__ cur, int* __restrict__ csr) {
  int e = blockIdx.x * 256 + threadIdx.x;
  int p = atomicAdd(&cur[src[e]], 1);
  csr[p] = dst[e];
}

// ---------------------------------------------------------------------------
// Fused segment-softmax attention gather: one wave per output node.
// ---------------------------------------------------------------------------
__global__ __launch_bounds__(256) void k_gather(
    const float* __restrict__ lin4, int qoff, int voff,
    const int* __restrict__ off, const int* __restrict__ csr_dst,
    float* __restrict__ outp, int ooff) {
  int node = blockIdx.x * 4 + (threadIdx.x >> 6);
  int l = threadIdx.x & 63;
  float qs = lin4[(size_t)node * 256 + qoff + l];
  int i0 = off[node], i1 = off[node + 1];
  float acc = 0.f, den = 0.f;
  for (int i = i0; i < i1; ++i) {
    int d = csr_dst[i];
    const float* base = lin4 + (size_t)d * 256;
    float qd = base[qoff + l];
    float vd = base[voff + l];
    float p = qs * qd;
#pragma unroll
    for (int o = 32; o > 0; o >>= 1) p += __shfl_xor(p, o, 64);
    float w = __expf(p * (1.0f / OUTW));
    den += w;
    acc += w * vd;
  }
  float r = den > 0.f ? 1.0f / den : 0.f;
  outp[(size_t)node * HIDE + ooff + l] = acc * r;
}

__global__ void k_pxbn(float* __restrict__ px, const float* __restrict__ g,
                       const float* __restrict__ b, const float* __restrict__ m,
                       const float* __restrict__ v) {
  int tid = blockIdx.x * 256 + threadIdx.x;
  int h = tid & 127;
  float x = px[tid];
  float sc = g[h] * rsqrtf(v[h] + EPSV);
  float y = sc * (x - m[h]) + b[h];
  px[tid] = y >= 0.f ? y : 0.01f * y;
}

// final: out = softmax((hyp+px) @ final_w + final_b)
__global__ __launch_bounds__(256) void k_final(
    const float* __restrict__ hyp, const float* __restrict__ px,
    const float* __restrict__ W, const float* __restrict__ b,
    float* __restrict__ out) {
  __shared__ float Wl[128 * 16];
  __shared__ float rl[16 * 129];
  int t = threadIdx.x;
  int n0 = blockIdx.x * 16;
#pragma unroll
  for (int i = 0; i < 8; ++i) Wl[t + 256 * i] = W[t + 256 * i];
#pragma unroll
  for (int i = 0; i < 8; ++i) {
    int v = t + 256 * i;
    int r = v >> 7, c = v & 127;
    rl[r * 129 + c] = hyp[(size_t)(n0 + r) * 128 + c] + px[(size_t)(n0 + r) * 128 + c];
  }
  __syncthreads();
  int r = t >> 4, cls = t & 15;
  float acc = b[cls];
  for (int k = 0; k < 128; ++k) acc += rl[r * 129 + k] * Wl[k * 16 + cls];
  float mx = acc;
#pragma unroll
  for (int o = 8; o > 0; o >>= 1) mx = fmaxf(mx, __shfl_xor(mx, o, 16));
  float e = expf(acc - mx), s = e;
#pragma unroll
  for (int o = 8; o > 0; o >>= 1) s += __shfl_xor(s, o, 16);
  out[(size_t)(n0 + r) * 16 + cls] = e / s;
}

// ---------------------------------------------------------------------------
extern "C" void kernel_launch(void* const* d_in, const int* in_sizes, int n_in,
                              void* d_out, int out_size, void* d_ws, size_t ws_size,
                              hipStream_t stream) {
  const float* x        = (const float*)d_in[0];
  const float* Q        = (const float*)d_in[1];
  const float* prelin_w = (const float*)d_in[2];
  const float* prelin_b = (const float*)d_in[3];
  const float* bn0_g    = (const float*)d_in[4];
  const float* bn0_b    = (const float*)d_in[5];
  const float* bn0_m    = (const float*)d_in[6];
  const float* bn0_v    = (const float*)d_in[7];
  const float* mmpn_w   = (const float*)d_in[8];
  const float* mmpn_b   = (const float*)d_in[9];
  const float* mmpn_bn_g= (const float*)d_in[10];
  const float* mmpn_bn_b= (const float*)d_in[11];
  const float* mmpn_bn_m= (const float*)d_in[12];
  const float* mmpn_bn_v= (const float*)d_in[13];
  const float* A_val    = (const float*)d_in[14];
  const float* imp_val  = (const float*)d_in[15];
  const float* px_rowv_w= (const float*)d_in[16];
  const float* px_rowv_b= (const float*)d_in[17];
  const float* px_colv_w= (const float*)d_in[18];
  const float* px_colv_b= (const float*)d_in[19];
  const float* px_rowq_w= (const float*)d_in[20];
  const float* px_rowq_b= (const float*)d_in[21];
  const float* px_colq_w= (const float*)d_in[22];
  const float* px_colq_b= (const float*)d_in[23];
  const float* px_bn_g  = (const float*)d_in[24];
  const float* px_bn_b  = (const float*)d_in[25];
  const float* px_bn_m  = (const float*)d_in[26];
  const float* px_bn_v  = (const float*)d_in[27];
  const float* final_w  = (const float*)d_in[28];
  const float* final_b  = (const float*)d_in[29];
  const int* A_src   = (const int*)d_in[30];
  const int* A_dst   = (const int*)d_in[31];
  const int* imp_src = (const int*)d_in[32];
  const int* imp_dst = (const int*)d_in[33];
  const int* row_src = (const int*)d_in[34];
  const int* row_dst = (const int*)d_in[35];
  const int* col_src = (const int*)d_in[36];
  const int* col_dst = (const int*)d_in[37];
  float* out = (float*)d_out;

  float* ws = (float*)d_ws;
  float* x0px = ws; ws += (size_t)N_PIX * HIDE;          // 8.4M fp32
  float* hyp  = ws; ws += (size_t)N_PIX * HIDE;          // 8.4M fp32 (aliases hp_part)
  float* hp_part = hyp;                                   // live only hpu->hpred
  float* big  = ws; ws += (size_t)32 * 1024 * 1024;       // 128 MB region
  ushort* Qt  = (ushort*)big;                              // phase 1: Qt bf16 [1024][65536]
  float* lin4 = big;                                       // phase 2: lin4 [N][256]
  int* off_row = (int*)(big + (size_t)N_PIX * 256);
  int* off_col = off_row + 65537;
  int* csr_row = off_col + 65537;
  int* csr_col = csr_row + E_PX;
  ushort* x0T = (ushort*)ws; ws += (size_t)HIDE * N_PIX / 2;  // bf16 [128][65536]
  ushort* hpT = (ushort*)ws; ws += (size_t)HIDE * S_SP / 2;   // bf16 [128][1024]
  float* csum = ws; ws += S_SP;
  float* hp   = ws; ws += (size_t)S_SP * HIDE;
  float* htmp = ws; ws += (size_t)S_SP * HIDE;   // reused as cur_row/cur_col
  float* agg  = ws; ws += (size_t)S_SP * HIDE;   // reused as cnt_row/cnt_col

  int* cnt_row = (int*)agg;
  int* cnt_col = (int*)agg + 65536;
  int* cur_row = (int*)htmp;
  int* cur_col = (int*)htmp + 65536;

  hipMemsetAsync(csum, 0, S_SP * sizeof(float), stream);

  k_cast<<<4096, 256, 0, stream>>>(Q, Qt, csum);
  k_x0<<<N_PIX / 32, 256, 0, stream>>>(x, prelin_w, prelin_b, bn0_g, bn0_b, bn0_m,
                                       bn0_v, x0px);
  k_xT<<<N_PIX / 256, 256, 0, stream>>>(x0px, x0T);
  k_hpu<<<256, 256, 0, stream>>>(Qt, x0T, hp_part);
  k_hpred<<<S_SP * HIDE / 256, 256, 0, stream>>>(hp_part, csum, hp);

  for (int i = 0; i < 5; ++i) {
    k_slin<<<S_SP / 32, 256, 0, stream>>>(hp, mmpn_w + (size_t)i * HIDE * HIDE,
                                          mmpn_b + i * HIDE, htmp);
    hipMemsetAsync(agg, 0, (size_t)S_SP * HIDE * sizeof(float), stream);
    k_edge_mmpn<<<(E_A + E_IMP) * HIDE / 256, 256, 0, stream>>>(
        htmp, hp, A_val, A_src, A_dst, imp_val, imp_src, imp_dst, agg);
    k_mmpn_bn<<<S_SP * HIDE / 256, 256, 0, stream>>>(
        agg, mmpn_bn_g + i * HIDE, mmpn_bn_b + i * HIDE, mmpn_bn_m + i * HIDE,
        mmpn_bn_v + i * HIDE, hp);
  }

  k_hpT<<<S_SP / 256, 256, 0, stream>>>(hp, hpT);
  k_hyp<<<N_PIX / 256, 256, 0, stream>>>(Q, hpT, hyp);

  // ---- CSR build (Qt region now reusable; cnt/cur alias agg/htmp) ----
  hipMemsetAsync(cnt_row, 0, 2 * 65536 * sizeof(int), stream);
  k_hist<<<E_PX / 256, 256, 0, stream>>>(row_src, cnt_row);
  k_hist<<<E_PX / 256, 256, 0, stream>>>(col_src, cnt_col);
  k_scan<<<1, 1024, 0, stream>>>(cnt_row, off_row, cur_row);
  k_scan<<<1, 1024, 0, stream>>>(cnt_col, off_col, cur_col);
  k_fill<<<E_PX / 256, 256, 0, stream>>>(row_src, row_dst, cur_row, csr_row);
  k_fill<<<E_PX / 256, 256, 0, stream>>>(col_src, col_dst, cur_col, csr_col);

  for (int j = 0; j < 2; ++j) {
    k_pxlin<<<N_PIX / 32, 256, 0, stream>>>(
        x0px, px_rowv_w + j * 8192, px_colv_w + j * 8192, px_rowq_w + j * 8192,
        px_colq_w + j * 8192, px_rowv_b + j * 64, px_colv_b + j * 64,
        px_rowq_b + j * 64, px_colq_b + j * 64, lin4);
    k_ln<<<N_PIX / 4, 256, 0, stream>>>(lin4);
    k_gather<<<N_PIX / 4, 256, 0, stream>>>(lin4, 128, 0, off_row, csr_row, x0px, 0);
    k_gather<<<N_PIX / 4, 256, 0, stream>>>(lin4, 192, 64, off_col, csr_col, x0px, 64);
    k_pxbn<<<N_PIX * HIDE / 256, 256, 0, stream>>>(x0px, px_bn_g + j * HIDE,
                                                   px_bn_b + j * HIDE,
                                                   px_bn_m + j * HIDE,
                                                   px_bn_v + j * HIDE);
  }

  k_final<<<N_PIX / 16, 256, 0, stream>>>(hyp, x0px, final_w, final_b, out);
}